// Round 5
// baseline (518.633 us; speedup 1.0000x reference)
//
#include <hip/hip_runtime.h>
#include <hip/hip_bf16.h>

#define N_NODES 50000
#define NIN 128
#define NOUT 64
#define EIN 32
#define N_EDGES 400000
#define N_UNITS (2 * N_EDGES)
#define ALPHA 0.2f

__device__ __forceinline__ int clampi(int x) {
  return min(max(x, 0), N_NODES - 1);
}

// ---------------------------------------------------------------------------
// Kernel 1: h = node_fts @ W + b (f32). One wave per node, lane j = column j.
// ---------------------------------------------------------------------------
__global__ __launch_bounds__(256) void k_gemm(const float* __restrict__ nf,
                                              const float* __restrict__ W,
                                              const float* __restrict__ b,
                                              float* __restrict__ h) {
  __shared__ float Ws[NIN * NOUT];  // 32 KB
  __shared__ float bs[NOUT];
  __shared__ float rows[4][NIN];
  int t = threadIdx.x;
#pragma unroll
  for (int n = 0; n < 32; ++n) Ws[t + n * 256] = W[t + n * 256];
  if (t < 64) bs[t] = b[t];
  __syncthreads();
  int j = t & 63, local = t >> 6;
  for (int v0 = blockIdx.x * 4; v0 < N_NODES; v0 += gridDim.x * 4) {
    int vload = v0 + (t >> 6);
    if (vload < N_NODES) {
      float2 p = ((const float2*)(nf + (size_t)vload * NIN))[t & 63];
      ((float2*)rows[t >> 6])[t & 63] = p;
    }
    __syncthreads();
    int v = v0 + local;
    if (v < N_NODES) {
      float acc = bs[j];
      const float* r = rows[local];
#pragma unroll
      for (int k = 0; k < NIN; k += 4) {
        float4 rk = *(const float4*)&r[k];
        acc += rk.x * Ws[(k + 0) * NOUT + j];
        acc += rk.y * Ws[(k + 1) * NOUT + j];
        acc += rk.z * Ws[(k + 2) * NOUT + j];
        acc += rk.w * Ws[(k + 3) * NOUT + j];
      }
      h[(size_t)v * NOUT + j] = acc;
    }
    __syncthreads();
  }
}

// ---------------------------------------------------------------------------
// Kernel 2: per node (one thread): A = h.a1, B = h.a2, hn = ||h||. Serial.
// ---------------------------------------------------------------------------
__global__ __launch_bounds__(256) void k_nodeprep(const float* __restrict__ h,
                                                  const float* __restrict__ a,
                                                  float* __restrict__ A,
                                                  float* __restrict__ B,
                                                  float* __restrict__ hn) {
  int v = blockIdx.x * blockDim.x + threadIdx.x;
  if (v >= N_NODES) return;
  const float* r = h + (size_t)v * NOUT;
  float pa = 0.f, pb = 0.f, pn = 0.f;
#pragma unroll
  for (int j = 0; j < NOUT; ++j) {
    float x = r[j];
    pa += x * a[j];
    pb += x * a[64 + j];
    pn += x * x;
  }
  A[v] = pa;
  B[v] = pb;
  hn[v] = sqrtf(pn);
}

// ---------------------------------------------------------------------------
// Kernel 3: per edge i: c = ef.a3; lrelu logits both directions -> l[];
// exp() atomics into att_sum (keyed by the unit's src).
// ---------------------------------------------------------------------------
__global__ __launch_bounds__(256) void k_edge1(const int* __restrict__ eb,
                                               const float* __restrict__ ef,
                                               const float* __restrict__ a,
                                               const float* __restrict__ A,
                                               const float* __restrict__ B,
                                               float* __restrict__ l,
                                               float* __restrict__ att_sum) {
  __shared__ float a3s[EIN];
  if (threadIdx.x < EIN) a3s[threadIdx.x] = a[128 + threadIdx.x];
  __syncthreads();
  int i = blockIdx.x * blockDim.x + threadIdx.x;
  if (i >= N_EDGES) return;
  int s = clampi(eb[2 * i]), d = clampi(eb[2 * i + 1]);
  const float4* efp = (const float4*)(ef + (size_t)i * EIN);
  float c = 0.f;
#pragma unroll
  for (int q = 0; q < 8; ++q) {
    float4 u = efp[q];
    c += u.x * a3s[4 * q + 0] + u.y * a3s[4 * q + 1] +
         u.z * a3s[4 * q + 2] + u.w * a3s[4 * q + 3];
  }
  float zf = A[s] + B[d] + c;  // forward unit: src=s, dst=d
  float zr = A[d] + B[s] + c;  // reverse unit: src=d, dst=s
  float lf = zf > 0.f ? zf : ALPHA * zf;
  float lr = zr > 0.f ? zr : ALPHA * zr;
  l[i] = lf;
  l[N_EDGES + i] = lr;
  atomicAdd(&att_sum[s], expf(lf));
  atomicAdd(&att_sum[d], expf(lr));
}

// ---------------------------------------------------------------------------
// Kernel 4: per unit: l[u] <- l[u] - log(att_sum[src[u]])   (= att_norm)
// ---------------------------------------------------------------------------
__global__ __launch_bounds__(256) void k_an(const int* __restrict__ eb,
                                            const float* __restrict__ att_sum,
                                            float* __restrict__ l) {
  int u = blockIdx.x * blockDim.x + threadIdx.x;
  if (u >= N_UNITS) return;
  int s = (u < N_EDGES) ? eb[2 * u] : eb[2 * (u - N_EDGES) + 1];
  s = clampi(s);
  l[u] = l[u] - logf(att_sum[s]);
}

// ---------------------------------------------------------------------------
// Kernel 5: scatter. Thread (u,j): out[src[u]*128 + j] += h[dst[u]][j]*an[u].
// msg accumulates IN d_out at the h-slot positions (f32 row stride 128).
// ---------------------------------------------------------------------------
__global__ __launch_bounds__(256) void k_scatter(const int* __restrict__ eb,
                                                 const float* __restrict__ l,
                                                 const float* __restrict__ h,
                                                 float* __restrict__ out) {
  long long tid = (long long)blockIdx.x * blockDim.x + threadIdx.x;
  int u = (int)(tid >> 6);
  int j = (int)(tid & 63);
  if (u >= N_UNITS) return;
  int s, d;
  if (u < N_EDGES) {
    s = eb[2 * u];
    d = eb[2 * u + 1];
  } else {
    int e = u - N_EDGES;
    s = eb[2 * e + 1];
    d = eb[2 * e];
  }
  s = clampi(s);
  d = clampi(d);
  float an = l[u];
  atomicAdd(&out[(size_t)s * 128 + j], h[(size_t)d * NOUT + j] * an);
}

// ---------------------------------------------------------------------------
// Kernel 6: variance sums over att_norm (=l), LDS block reduce, f64 atomics.
// ---------------------------------------------------------------------------
__global__ __launch_bounds__(256) void k_sums(const float* __restrict__ l,
                                              double* __restrict__ sums) {
  __shared__ double s1[256], s2[256];
  int u = blockIdx.x * blockDim.x + threadIdx.x;
  float x = (u < N_UNITS) ? l[u] : 0.f;
  s1[threadIdx.x] = (double)x;
  s2[threadIdx.x] = (double)x * (double)x;
  __syncthreads();
  for (int o = 128; o > 0; o >>= 1) {
    if (threadIdx.x < o) {
      s1[threadIdx.x] += s1[threadIdx.x + o];
      s2[threadIdx.x] += s2[threadIdx.x + o];
    }
    __syncthreads();
  }
  if (threadIdx.x == 0) {
    atomicAdd(&sums[0], s1[0]);
    atomicAdd(&sums[1], s2[0]);
  }
}

// ---------------------------------------------------------------------------
// Kernel 7: per node (one thread): read msg row from out[128v..128v+64),
// normalize, then overwrite out row v with f32 [h_v | agg_v]. Same thread
// reads then writes -> no cross-row hazard.
// ---------------------------------------------------------------------------
__global__ __launch_bounds__(256) void k_final(const float* __restrict__ h,
                                               const float* __restrict__ hn,
                                               const float* __restrict__ scale_p,
                                               float* __restrict__ out) {
  int v = blockIdx.x * blockDim.x + threadIdx.x;
  if (v >= N_NODES) return;
  float scale = scale_p[0];
  float* row = out + (size_t)v * 128;
  float m[NOUT];
  float nrm = 0.f;
#pragma unroll
  for (int j = 0; j < NOUT; ++j) {
    m[j] = row[j];
    nrm += m[j] * m[j];
  }
  nrm = sqrtf(nrm);
  float fac = hn[v] * scale / fmaxf(nrm, 1e-12f);
  const float* hr = h + (size_t)v * NOUT;
#pragma unroll
  for (int j = 0; j < NOUT; ++j) row[j] = hr[j];
#pragma unroll
  for (int j = 0; j < NOUT; ++j) row[64 + j] = m[j] * fac;
}

// ---------------------------------------------------------------------------
// Kernel 8: att_var -> out[6,400,000] (f32)
// ---------------------------------------------------------------------------
__global__ void k_var(const double* __restrict__ sums,
                      float* __restrict__ out) {
  if (threadIdx.x == 0 && blockIdx.x == 0) {
    double M = (double)N_UNITS;
    double var = (sums[1] - sums[0] * sums[0] / M) / (M - 1.0);
    out[(size_t)N_NODES * 128] = (float)var;
  }
}

extern "C" void kernel_launch(void* const* d_in, const int* in_sizes, int n_in,
                              void* d_out, int out_size, void* d_ws,
                              size_t ws_size, hipStream_t stream) {
  const float* nf = (const float*)d_in[0];
  const float* ef = (const float*)d_in[1];
  const int* eb = (const int*)d_in[2];
  const float* W = (const float*)d_in[3];
  const float* b = (const float*)d_in[4];
  const float* a = (const float*)d_in[5];
  const float* scale_p = (const float*)d_in[6];
  float* out = (float*)d_out;  // 6,400,001 f32

  char* ws = (char*)d_ws;
  float* h = (float*)(ws + 0);              // 12,800,000 B
  float* l = (float*)(ws + 12800000);       //  3,200,000 B
  float* A = (float*)(ws + 16000000);       //    200,000 B
  float* B = (float*)(ws + 16200000);       //    200,000 B
  float* hn = (float*)(ws + 16400000);      //    200,000 B
  float* att_sum = (float*)(ws + 16600000); //    200,000 B
  double* sums = (double*)(ws + 16800000);  //         16 B

  hipMemsetAsync(d_out, 0, 25600004, stream);       // zero msg accumulator (f32 out)
  hipMemsetAsync(ws + 16600000, 0, 200016, stream); // zero att_sum + sums

  k_gemm<<<256, 256, 0, stream>>>(nf, W, b, h);
  k_nodeprep<<<(N_NODES + 255) / 256, 256, 0, stream>>>(h, a, A, B, hn);
  k_edge1<<<(N_EDGES + 255) / 256, 256, 0, stream>>>(eb, ef, a, A, B, l, att_sum);
  k_an<<<(N_UNITS + 255) / 256, 256, 0, stream>>>(eb, att_sum, l);
  k_scatter<<<(int)(((long long)N_UNITS * 64 + 255) / 256), 256, 0, stream>>>(eb, l, h, out);
  k_sums<<<(N_UNITS + 255) / 256, 256, 0, stream>>>(l, sums);
  k_final<<<(N_NODES + 255) / 256, 256, 0, stream>>>(h, hn, scale_p, out);
  k_var<<<1, 64, 0, stream>>>(sums, out);
}

// Round 6
// 517.909 us; speedup vs baseline: 1.0014x; 1.0014x over previous
//
#include <hip/hip_runtime.h>
#include <hip/hip_bf16.h>

#define N_NODES 50000
#define NIN 128
#define NOUT 64
#define EIN 32
#define N_EDGES 400000
#define N_UNITS (2 * N_EDGES)
#define ALPHA 0.2f

__device__ __forceinline__ int clampi(int x) {
  return min(max(x, 0), N_NODES - 1);
}

// ---------------------------------------------------------------------------
// Kernel 1: h = node_fts @ W + b (f32), fused per-node A = h.a1, B = h.a2,
// hn = ||h||. One wave per node, lane j = column j. 1024 blocks = 4/CU.
// ---------------------------------------------------------------------------
__global__ __launch_bounds__(256) void k_gemm(
    const float* __restrict__ nf, const float* __restrict__ W,
    const float* __restrict__ b, const float* __restrict__ a,
    float* __restrict__ h, float* __restrict__ A, float* __restrict__ B,
    float* __restrict__ hn) {
  __shared__ float Ws[NIN * NOUT];  // 32 KB
  __shared__ float bs[NOUT], a1s[NOUT], a2s[NOUT];
  __shared__ float rows[4][NIN];
  int t = threadIdx.x;
#pragma unroll
  for (int n = 0; n < 32; ++n) Ws[t + n * 256] = W[t + n * 256];
  if (t < 64) { bs[t] = b[t]; a1s[t] = a[t]; a2s[t] = a[64 + t]; }
  __syncthreads();
  int j = t & 63, local = t >> 6;
  for (int v0 = blockIdx.x * 4; v0 < N_NODES; v0 += gridDim.x * 4) {
    int vload = v0 + (t >> 6);
    if (vload < N_NODES) {
      float2 p = ((const float2*)(nf + (size_t)vload * NIN))[t & 63];
      ((float2*)rows[t >> 6])[t & 63] = p;
    }
    __syncthreads();
    int v = v0 + local;
    if (v < N_NODES) {
      float acc = bs[j];
      const float* r = rows[local];
#pragma unroll
      for (int k = 0; k < NIN; k += 4) {
        float4 rk = *(const float4*)&r[k];
        acc += rk.x * Ws[(k + 0) * NOUT + j];
        acc += rk.y * Ws[(k + 1) * NOUT + j];
        acc += rk.z * Ws[(k + 2) * NOUT + j];
        acc += rk.w * Ws[(k + 3) * NOUT + j];
      }
      h[(size_t)v * NOUT + j] = acc;
      float pa = acc * a1s[j], pb = acc * a2s[j], pn = acc * acc;
      for (int o = 32; o > 0; o >>= 1) {
        pa += __shfl_down(pa, o, 64);
        pb += __shfl_down(pb, o, 64);
        pn += __shfl_down(pn, o, 64);
      }
      if (j == 0) { A[v] = pa; B[v] = pb; hn[v] = sqrtf(pn); }
    }
    __syncthreads();
  }
}

// ---------------------------------------------------------------------------
// Kernel 2: per edge: logits both directions -> l[]; exp atomics into
// att_sum; degree count atomics.
// ---------------------------------------------------------------------------
__global__ __launch_bounds__(256) void k_edge1(
    const int* __restrict__ eb, const float* __restrict__ ef,
    const float* __restrict__ a, const float* __restrict__ A,
    const float* __restrict__ B, float* __restrict__ l,
    float* __restrict__ att_sum, int* __restrict__ count) {
  __shared__ float a3s[EIN];
  if (threadIdx.x < EIN) a3s[threadIdx.x] = a[128 + threadIdx.x];
  __syncthreads();
  int i = blockIdx.x * blockDim.x + threadIdx.x;
  if (i >= N_EDGES) return;
  int s = clampi(eb[2 * i]), d = clampi(eb[2 * i + 1]);
  const float4* efp = (const float4*)(ef + (size_t)i * EIN);
  float c = 0.f;
#pragma unroll
  for (int q = 0; q < 8; ++q) {
    float4 u = efp[q];
    c += u.x * a3s[4 * q + 0] + u.y * a3s[4 * q + 1] +
         u.z * a3s[4 * q + 2] + u.w * a3s[4 * q + 3];
  }
  float zf = A[s] + B[d] + c;  // forward: src=s, dst=d
  float zr = A[d] + B[s] + c;  // reverse: src=d, dst=s
  float lf = zf > 0.f ? zf : ALPHA * zf;
  float lr = zr > 0.f ? zr : ALPHA * zr;
  l[i] = lf;
  l[N_EDGES + i] = lr;
  atomicAdd(&att_sum[s], expf(lf));
  atomicAdd(&att_sum[d], expf(lr));
  atomicAdd(&count[s], 1);
  atomicAdd(&count[d], 1);
}

// ---------------------------------------------------------------------------
// Kernel 3: single-block exclusive scan of count[50000] -> off, cur.
// ---------------------------------------------------------------------------
__global__ __launch_bounds__(1024) void k_scan(const int* __restrict__ count,
                                               int* __restrict__ off,
                                               int* __restrict__ cur) {
  __shared__ int ls[1024];
  int t = threadIdx.x;
  const int CH = 49;  // ceil(50000/1024)
  int start = t * CH, end = min(start + CH, N_NODES);
  int s = 0;
  for (int i = start; i < end; ++i) s += count[i];
  ls[t] = s;
  __syncthreads();
  for (int o = 1; o < 1024; o <<= 1) {
    int v = (t >= o) ? ls[t - o] : 0;
    __syncthreads();
    ls[t] += v;
    __syncthreads();
  }
  int run = (t == 0) ? 0 : ls[t - 1];
  for (int i = start; i < end; ++i) {
    off[i] = run;
    cur[i] = run;
    run += count[i];
  }
  if (t == 1023) off[N_NODES] = ls[1023];
}

// ---------------------------------------------------------------------------
// Kernel 4: att_norm = l[u] - log(att_sum[src]); CSR scatter (dst, an);
// fused f64 variance sums (LDS block reduce, 2 atomics/block).
// ---------------------------------------------------------------------------
__global__ __launch_bounds__(256) void k_edge2(
    const int* __restrict__ eb, const float* __restrict__ l,
    const float* __restrict__ att_sum, int* __restrict__ cur,
    int* __restrict__ csr_d, float* __restrict__ csr_a,
    double* __restrict__ sums) {
  __shared__ double s1[256], s2[256];
  int u = blockIdx.x * blockDim.x + threadIdx.x;
  float an = 0.f;
  if (u < N_UNITS) {
    int s, d;
    if (u < N_EDGES) {
      s = eb[2 * u];
      d = eb[2 * u + 1];
    } else {
      int e = u - N_EDGES;
      s = eb[2 * e + 1];
      d = eb[2 * e];
    }
    s = clampi(s);
    d = clampi(d);
    an = l[u] - logf(att_sum[s]);
    int pos = atomicAdd(&cur[s], 1);
    csr_d[pos] = d;
    csr_a[pos] = an;
  }
  s1[threadIdx.x] = (double)an;
  s2[threadIdx.x] = (double)an * (double)an;
  __syncthreads();
  for (int o = 128; o > 0; o >>= 1) {
    if (threadIdx.x < o) {
      s1[threadIdx.x] += s1[threadIdx.x + o];
      s2[threadIdx.x] += s2[threadIdx.x + o];
    }
    __syncthreads();
  }
  if (threadIdx.x == 0) {
    atomicAdd(&sums[0], s1[0]);
    atomicAdd(&sums[1], s2[0]);
  }
}

// ---------------------------------------------------------------------------
// Kernel 5: one wave per node: msg_j = sum_k h[csr_d[k]][j]*csr_a[k];
// agg = msg/max(||msg||,eps) * hn[v]*scale; out row v = f32 [h_v | agg_v].
// ---------------------------------------------------------------------------
__global__ __launch_bounds__(256) void k_gather(
    const float* __restrict__ h, const float* __restrict__ hn,
    const int* __restrict__ off, const int* __restrict__ csr_d,
    const float* __restrict__ csr_a, const float* __restrict__ scale_p,
    float* __restrict__ out) {
  float scale = scale_p[0];
  int j = threadIdx.x & 63;
  int v = blockIdx.x * (blockDim.x >> 6) + (threadIdx.x >> 6);
  if (v >= N_NODES) return;
  int k0 = off[v], k1 = off[v + 1];
  float msg = 0.f;
  for (int kb = k0; kb < k1; kb += 64) {
    int nk = min(64, k1 - kb);
    int idx = 0;
    float an = 0.f;
    if (j < nk) { idx = csr_d[kb + j]; an = csr_a[kb + j]; }
    for (int kk = 0; kk < nk; ++kk) {
      int dk = __shfl(idx, kk, 64);
      float ak = __shfl(an, kk, 64);
      msg += h[(size_t)dk * NOUT + j] * ak;
    }
  }
  float nrm = msg * msg;
  for (int o = 32; o > 0; o >>= 1) nrm += __shfl_xor(nrm, o, 64);
  nrm = sqrtf(nrm);
  float fac = hn[v] * scale / fmaxf(nrm, 1e-12f);
  out[(size_t)v * 128 + j] = h[(size_t)v * NOUT + j];
  out[(size_t)v * 128 + 64 + j] = msg * fac;
}

// ---------------------------------------------------------------------------
// Kernel 6: att_var -> out[6,400,000] (f32)
// ---------------------------------------------------------------------------
__global__ void k_var(const double* __restrict__ sums,
                      float* __restrict__ out) {
  if (threadIdx.x == 0 && blockIdx.x == 0) {
    double M = (double)N_UNITS;
    double var = (sums[1] - sums[0] * sums[0] / M) / (M - 1.0);
    out[(size_t)N_NODES * 128] = (float)var;
  }
}

extern "C" void kernel_launch(void* const* d_in, const int* in_sizes, int n_in,
                              void* d_out, int out_size, void* d_ws,
                              size_t ws_size, hipStream_t stream) {
  const float* nf = (const float*)d_in[0];
  const float* ef = (const float*)d_in[1];
  const int* eb = (const int*)d_in[2];
  const float* W = (const float*)d_in[3];
  const float* b = (const float*)d_in[4];
  const float* a = (const float*)d_in[5];
  const float* scale_p = (const float*)d_in[6];
  float* out = (float*)d_out;  // 6,400,001 f32

  char* ws = (char*)d_ws;
  float* h = (float*)(ws + 0);              // 12,800,000 B
  float* l = (float*)(ws + 12800000);       //  3,200,000 B
  int* csr_d = (int*)(ws + 16000000);       //  3,200,000 B
  float* csr_a = (float*)(ws + 19200000);   //  3,200,000 B
  float* A = (float*)(ws + 22400000);       //    200,000 B
  float* B = (float*)(ws + 22600000);       //    200,000 B
  float* hn = (float*)(ws + 22800000);      //    200,000 B
  int* off = (int*)(ws + 23000000);         //    200,016 B (50001 + pad)
  int* cur = (int*)(ws + 23200016);         //    200,000 B
  int* count = (int*)(ws + 23400016);       //    200,000 B
  float* att_sum = (float*)(ws + 23600016); //    200,000 B
  double* sums = (double*)(ws + 23800016);  //         16 B

  // zero count, att_sum, sums (contiguous)
  hipMemsetAsync(ws + 23400016, 0, 400016, stream);

  k_gemm<<<1024, 256, 0, stream>>>(nf, W, b, a, h, A, B, hn);
  k_edge1<<<(N_EDGES + 255) / 256, 256, 0, stream>>>(eb, ef, a, A, B, l,
                                                     att_sum, count);
  k_scan<<<1, 1024, 0, stream>>>(count, off, cur);
  k_edge2<<<(N_UNITS + 255) / 256, 256, 0, stream>>>(eb, l, att_sum, cur,
                                                     csr_d, csr_a, sums);
  k_gather<<<12500, 256, 0, stream>>>(h, hn, off, csr_d, csr_a, scale_p, out);
  k_var<<<1, 64, 0, stream>>>(sums, out);
}

// Round 7
// 397.816 us; speedup vs baseline: 1.3037x; 1.3019x over previous
//
#include <hip/hip_runtime.h>
#include <hip/hip_bf16.h>

#define N_NODES 50000
#define NIN 128
#define NOUT 64
#define EIN 32
#define N_EDGES 400000
#define N_UNITS (2 * N_EDGES)
#define ALPHA 0.2f
#define NBINS 16

__device__ __forceinline__ int clampi(int x) {
  return min(max(x, 0), N_NODES - 1);
}

// ---------------------------------------------------------------------------
// Kernel 1: h = node_fts @ W + b (f32), fused A = h.a1, B = h.a2, hn = ||h||.
// One wave per node, lane j = column j.
// ---------------------------------------------------------------------------
__global__ __launch_bounds__(256) void k_gemm(
    const float* __restrict__ nf, const float* __restrict__ W,
    const float* __restrict__ b, const float* __restrict__ a,
    float* __restrict__ h, float* __restrict__ A, float* __restrict__ B,
    float* __restrict__ hn) {
  __shared__ float Ws[NIN * NOUT];  // 32 KB
  __shared__ float bs[NOUT], a1s[NOUT], a2s[NOUT];
  __shared__ float rows[4][NIN];
  int t = threadIdx.x;
#pragma unroll
  for (int n = 0; n < 32; ++n) Ws[t + n * 256] = W[t + n * 256];
  if (t < 64) { bs[t] = b[t]; a1s[t] = a[t]; a2s[t] = a[64 + t]; }
  __syncthreads();
  int j = t & 63, local = t >> 6;
  for (int v0 = blockIdx.x * 4; v0 < N_NODES; v0 += gridDim.x * 4) {
    int vload = v0 + (t >> 6);
    if (vload < N_NODES) {
      float2 p = ((const float2*)(nf + (size_t)vload * NIN))[t & 63];
      ((float2*)rows[t >> 6])[t & 63] = p;
    }
    __syncthreads();
    int v = v0 + local;
    if (v < N_NODES) {
      float acc = bs[j];
      const float* r = rows[local];
#pragma unroll
      for (int k = 0; k < NIN; k += 4) {
        float4 rk = *(const float4*)&r[k];
        acc += rk.x * Ws[(k + 0) * NOUT + j];
        acc += rk.y * Ws[(k + 1) * NOUT + j];
        acc += rk.z * Ws[(k + 2) * NOUT + j];
        acc += rk.w * Ws[(k + 3) * NOUT + j];
      }
      h[(size_t)v * NOUT + j] = acc;
      float pa = acc * a1s[j], pb = acc * a2s[j], pn = acc * acc;
      for (int o = 32; o > 0; o >>= 1) {
        pa += __shfl_down(pa, o, 64);
        pb += __shfl_down(pb, o, 64);
        pn += __shfl_down(pn, o, 64);
      }
      if (j == 0) { A[v] = pa; B[v] = pb; hn[v] = sqrtf(pn); }
    }
    __syncthreads();
  }
}

// ---------------------------------------------------------------------------
// Kernel 2: per edge: logits both directions -> l[]; exp atomics into
// att_sum; degree count atomics whose RETURN VALUE is the unit's within-
// segment rank (stored for atomic-free CSR placement in k_edge2).
// ---------------------------------------------------------------------------
__global__ __launch_bounds__(256) void k_edge1(
    const int* __restrict__ eb, const float* __restrict__ ef,
    const float* __restrict__ a, const float* __restrict__ A,
    const float* __restrict__ B, float* __restrict__ l,
    int* __restrict__ rank, float* __restrict__ att_sum,
    int* __restrict__ count) {
  __shared__ float a3s[EIN];
  if (threadIdx.x < EIN) a3s[threadIdx.x] = a[128 + threadIdx.x];
  __syncthreads();
  int i = blockIdx.x * blockDim.x + threadIdx.x;
  if (i >= N_EDGES) return;
  int2 sd = ((const int2*)eb)[i];
  int s = clampi(sd.x), d = clampi(sd.y);
  const float4* efp = (const float4*)(ef + (size_t)i * EIN);
  float c = 0.f;
#pragma unroll
  for (int q = 0; q < 8; ++q) {
    float4 u = efp[q];
    c += u.x * a3s[4 * q + 0] + u.y * a3s[4 * q + 1] +
         u.z * a3s[4 * q + 2] + u.w * a3s[4 * q + 3];
  }
  float zf = A[s] + B[d] + c;  // forward: src=s, dst=d
  float zr = A[d] + B[s] + c;  // reverse: src=d, dst=s
  float lf = zf > 0.f ? zf : ALPHA * zf;
  float lr = zr > 0.f ? zr : ALPHA * zr;
  l[i] = lf;
  l[N_EDGES + i] = lr;
  atomicAdd(&att_sum[s], expf(lf));
  atomicAdd(&att_sum[d], expf(lr));
  rank[i] = atomicAdd(&count[s], 1);
  rank[N_EDGES + i] = atomicAdd(&count[d], 1);
}

// ---------------------------------------------------------------------------
// Kernel 3: single-block exclusive scan of count[50000] -> off.
// ---------------------------------------------------------------------------
__global__ __launch_bounds__(1024) void k_scan(const int* __restrict__ count,
                                               int* __restrict__ off) {
  __shared__ int ls[1024];
  int t = threadIdx.x;
  const int CH = 49;  // ceil(50000/1024)
  int start = t * CH, end = min(start + CH, N_NODES);
  int s = 0;
  for (int i = start; i < end; ++i) s += count[i];
  ls[t] = s;
  __syncthreads();
  for (int o = 1; o < 1024; o <<= 1) {
    int v = (t >= o) ? ls[t - o] : 0;
    __syncthreads();
    ls[t] += v;
    __syncthreads();
  }
  int run = (t == 0) ? 0 : ls[t - 1];
  for (int i = start; i < end; ++i) {
    off[i] = run;
    run += count[i];
  }
  if (t == 1023) off[N_NODES] = ls[1023];
}

// ---------------------------------------------------------------------------
// Kernel 4: an = l[u] - log(att_sum[src]); single packed int2 store at
// off[src]+rank[u] (atomic-free); binned f64 variance sums.
// ---------------------------------------------------------------------------
__global__ __launch_bounds__(256) void k_edge2(
    const int* __restrict__ eb, const float* __restrict__ l,
    const int* __restrict__ rank, const float* __restrict__ att_sum,
    const int* __restrict__ off, int2* __restrict__ csr,
    double* __restrict__ sums) {
  __shared__ double s1[256], s2[256];
  int u = blockIdx.x * blockDim.x + threadIdx.x;
  float an = 0.f;
  if (u < N_UNITS) {
    int s, d;
    if (u < N_EDGES) {
      int2 sd = ((const int2*)eb)[u];
      s = sd.x; d = sd.y;
    } else {
      int2 sd = ((const int2*)eb)[u - N_EDGES];
      s = sd.y; d = sd.x;
    }
    s = clampi(s);
    d = clampi(d);
    an = l[u] - logf(att_sum[s]);
    int pos = off[s] + rank[u];
    csr[pos] = make_int2(d, __float_as_int(an));
  }
  s1[threadIdx.x] = (double)an;
  s2[threadIdx.x] = (double)an * (double)an;
  __syncthreads();
  for (int o = 128; o > 0; o >>= 1) {
    if (threadIdx.x < o) {
      s1[threadIdx.x] += s1[threadIdx.x + o];
      s2[threadIdx.x] += s2[threadIdx.x + o];
    }
    __syncthreads();
  }
  if (threadIdx.x == 0) {
    int bin = blockIdx.x & (NBINS - 1);
    atomicAdd(&sums[2 * bin], s1[0]);
    atomicAdd(&sums[2 * bin + 1], s2[0]);
  }
}

// ---------------------------------------------------------------------------
// Kernel 5: one wave per node: msg_j = sum_k h[dst_k][j]*an_k;
// agg = msg/max(||msg||,eps)*hn[v]*scale; out row v = f32 [h_v | agg_v].
// ---------------------------------------------------------------------------
__global__ __launch_bounds__(256) void k_gather(
    const float* __restrict__ h, const float* __restrict__ hn,
    const int* __restrict__ off, const int2* __restrict__ csr,
    const float* __restrict__ scale_p, float* __restrict__ out) {
  float scale = scale_p[0];
  int j = threadIdx.x & 63;
  int v = blockIdx.x * (blockDim.x >> 6) + (threadIdx.x >> 6);
  if (v >= N_NODES) return;
  int k0 = off[v], k1 = off[v + 1];
  float msg = 0.f;
  for (int kb = k0; kb < k1; kb += 64) {
    int nk = min(64, k1 - kb);
    int idx = 0;
    float an = 0.f;
    if (j < nk) {
      int2 e = csr[kb + j];
      idx = e.x;
      an = __int_as_float(e.y);
    }
    for (int kk = 0; kk < nk; ++kk) {
      int dk = __shfl(idx, kk, 64);
      float ak = __shfl(an, kk, 64);
      msg += h[(size_t)dk * NOUT + j] * ak;
    }
  }
  float nrm = msg * msg;
  for (int o = 32; o > 0; o >>= 1) nrm += __shfl_xor(nrm, o, 64);
  nrm = sqrtf(nrm);
  float fac = hn[v] * scale / fmaxf(nrm, 1e-12f);
  out[(size_t)v * 128 + j] = h[(size_t)v * NOUT + j];
  out[(size_t)v * 128 + 64 + j] = msg * fac;
}

// ---------------------------------------------------------------------------
// Kernel 6: reduce 16 bins -> att_var -> out[6,400,000] (f32)
// ---------------------------------------------------------------------------
__global__ void k_var(const double* __restrict__ sums,
                      float* __restrict__ out) {
  if (threadIdx.x == 0 && blockIdx.x == 0) {
    double S1 = 0.0, S2 = 0.0;
#pragma unroll
    for (int i = 0; i < NBINS; ++i) {
      S1 += sums[2 * i];
      S2 += sums[2 * i + 1];
    }
    double M = (double)N_UNITS;
    double var = (S2 - S1 * S1 / M) / (M - 1.0);
    out[(size_t)N_NODES * 128] = (float)var;
  }
}

extern "C" void kernel_launch(void* const* d_in, const int* in_sizes, int n_in,
                              void* d_out, int out_size, void* d_ws,
                              size_t ws_size, hipStream_t stream) {
  const float* nf = (const float*)d_in[0];
  const float* ef = (const float*)d_in[1];
  const int* eb = (const int*)d_in[2];
  const float* W = (const float*)d_in[3];
  const float* b = (const float*)d_in[4];
  const float* a = (const float*)d_in[5];
  const float* scale_p = (const float*)d_in[6];
  float* out = (float*)d_out;  // 6,400,001 f32

  char* ws = (char*)d_ws;
  float* h = (float*)(ws + 0);              // 12,800,000 B
  float* l = (float*)(ws + 12800000);       //  3,200,000 B
  int* rank = (int*)(ws + 16000000);        //  3,200,000 B
  int2* csr = (int2*)(ws + 19200000);       //  6,400,000 B
  float* A = (float*)(ws + 25600000);       //    200,000 B
  float* B = (float*)(ws + 25800000);       //    200,000 B
  float* hn = (float*)(ws + 26000000);      //    200,000 B
  int* off = (int*)(ws + 26200000);         //    200,016 B (50001 + pad)
  int* count = (int*)(ws + 26400016);       //    200,000 B
  float* att_sum = (float*)(ws + 26600016); //    200,000 B
  double* sums = (double*)(ws + 26800016);  //        256 B (16 bins x 2)

  // zero count, att_sum, sums (contiguous)
  hipMemsetAsync(ws + 26400016, 0, 400256, stream);

  k_gemm<<<1024, 256, 0, stream>>>(nf, W, b, a, h, A, B, hn);
  k_edge1<<<(N_EDGES + 255) / 256, 256, 0, stream>>>(eb, ef, a, A, B, l, rank,
                                                     att_sum, count);
  k_scan<<<1, 1024, 0, stream>>>(count, off);
  k_edge2<<<(N_UNITS + 255) / 256, 256, 0, stream>>>(eb, l, rank, att_sum, off,
                                                     csr, sums);
  k_gather<<<12500, 256, 0, stream>>>(h, hn, off, csr, scale_p, out);
  k_var<<<1, 64, 0, stream>>>(sums, out);
}